// Round 17
// baseline (196.990 us; speedup 1.0000x reference)
//
#include <hip/hip_runtime.h>
#include <hip/hip_bf16.h>
#include <math.h>

#define B_    2048
#define V_    5023
#define N3    15069      // V*3
#define VOFF  30861312   // B_*N3, start of rot_mats in d_out

// GEMM geometry: block = 256 rows x 96 cols, 4 waves (each 64 rows), BK=32
#define BM    256
#define BN    96
#define NKC   14         // 448/32
#define NBX   157
#define NBY   8

// ws layout (float units) — R12-verbatim
#define OFF_CBT    0           // bf16 Cmat tiled: 8*14*16KB = 1835008 B
#define OFF_SDTT   458752      // bf16 SDT tiled: 157*14*6KB
#define OFF_JSP    0           // overlay: [512][6016] partials (consumed before CBT/SDTT written)
#define OFF_JS     3834880     // [15*400]
#define OFF_JT     3840880     // [15]
#define OFF_A      3840896     // [2048][60]

#define NCH 512
#define CHV 10

typedef __attribute__((ext_vector_type(8))) short short8;
typedef __attribute__((ext_vector_type(4))) float f32x4;

typedef __attribute__((address_space(1))) const void gvoid_t;
typedef __attribute__((address_space(3))) void lvoid_t;
#define GLDS16(g, l) __builtin_amdgcn_global_load_lds((gvoid_t*)(g), (lvoid_t*)(l), 16, 0, 0)

// ---------------- K1: JS/Jt partials; SD streamed once (R12-verbatim)
__global__ void __launch_bounds__(512) k_js(
    const float* __restrict__ Jreg, const float* __restrict__ SD,
    const float* __restrict__ VT, float* __restrict__ ws) {
    int ch = blockIdx.x;
    int v0 = ch * CHV;
    int t = threadIdx.x;
    __shared__ float jw[5][CHV];
    for (int s = t; s < 5 * CHV; s += 512) {
        int j = s / CHV, vi = s % CHV;
        int v = v0 + vi;
        jw[j][vi] = (v < V_) ? Jreg[j * V_ + v] : 0.f;
    }
    __syncthreads();
    int nv = min(V_ - v0, CHV);
    if (t < 400) {
        float acc[15];
        #pragma unroll
        for (int i = 0; i < 15; ++i) acc[i] = 0.f;
        for (int vi = 0; vi < nv; ++vi) {
            int v = v0 + vi;
            float s0 = SD[(v * 3 + 0) * 400 + t];
            float s1 = SD[(v * 3 + 1) * 400 + t];
            float s2 = SD[(v * 3 + 2) * 400 + t];
            #pragma unroll
            for (int j = 0; j < 5; ++j) {
                float jr = jw[j][vi];
                acc[j * 3 + 0] += jr * s0;
                acc[j * 3 + 1] += jr * s1;
                acc[j * 3 + 2] += jr * s2;
            }
        }
        #pragma unroll
        for (int i = 0; i < 15; ++i)
            ws[OFF_JSP + ch * 6016 + i * 400 + t] = acc[i];
    } else if (t >= 448 && t < 463) {
        int jk = t - 448, j = jk / 3, k = jk % 3;
        float a = 0.f;
        for (int vi = 0; vi < nv; ++vi)
            a += jw[j][vi] * VT[(v0 + vi) * 3 + k];
        ws[OFF_JSP + ch * 6016 + 6000 + jk] = a;
    }
}

// ---------------- K2: reduce partials (R12-verbatim)
__global__ void k_js_reduce(float* __restrict__ ws) {
    int r = blockIdx.x * 256 + threadIdx.x;
    if (r >= 6016) return;
    float s = 0.f;
    for (int ch = 0; ch < NCH; ++ch) s += ws[OFF_JSP + ch * 6016 + r];
    if (r < 6000) ws[OFF_JS + r] = s;
    else if (r < 6015) ws[OFF_JT + (r - 6000)] = s;
}

// ---------------- K3: SDT fragment-tiled via LDS transpose (R12-verbatim)
__global__ void __launch_bounds__(256) k_sdt_lds(
    const float* __restrict__ SD, const float* __restrict__ PD,
    float* __restrict__ ws) {
    __shared__ __hip_bfloat16 lb[16][456];
    int bid = blockIdx.x;
    int bx = bid / 6, jl = bid % 6;
    int n0 = bx * 96 + jl * 16;
    int tid = threadIdx.x;
    for (int s = tid; s < 16 * 400; s += 256) {
        int r = s / 400, c = s % 400;
        int n = n0 + r;
        lb[r][c] = __float2bfloat16((n < N3) ? SD[n * 400 + c] : 0.f);
    }
    for (int s = tid; s < 36 * 16; s += 256) {
        int p = s / 16, r = s % 16;
        int n = n0 + r;
        lb[r][400 + p] = __float2bfloat16((n < N3) ? PD[p * N3 + n] : 0.f);
    }
    for (int s = tid; s < 12 * 16; s += 256) {
        int c = s / 16, r = s % 16;
        lb[r][436 + c] = __float2bfloat16(0.f);
    }
    __syncthreads();
    uint4* sdtt = (uint4*)((char*)ws + (size_t)OFF_SDTT * 4);
    for (int s = tid; s < NKC * 64; s += 256) {
        int kc = s >> 6, lane = s & 63;
        int r = lane & 15;
        int k0 = kc * 32 + (lane >> 4) * 8;
        uint4 val = *(const uint4*)&lb[r][k0];
        sdtt[((size_t)(bx * NKC + kc) * 6 + jl) * 64 + lane] = val;
    }
}

// ---------------- K4: Cmat (betas) in fragment-tiled order (R12-verbatim)
__global__ void k_cbt_tiled(const float* __restrict__ sh, const float* __restrict__ ex,
                            float* __restrict__ ws) {
    int id = blockIdx.x * 256 + threadIdx.x;
    if (id >= NBY * NKC * 16 * 64) return;
    int lane = id & 63;
    int t = id >> 6;
    int mf = t & 15; t >>= 4;
    int kc = t % NKC, by = t / NKC;
    int b = by * BM + mf * 16 + (lane & 15);
    int k0 = kc * 32 + (lane >> 4) * 8;
    union { __hip_bfloat16 h[8]; uint4 u; } pk;
    #pragma unroll
    for (int e = 0; e < 8; ++e) {
        int k = k0 + e;
        float v = 0.f;
        if (k < 300) v = sh[b * 300 + k];
        else if (k < 400) v = ex[b * 100 + (k - 300)];
        pk.h[e] = __float2bfloat16(v);
    }
    ((uint4*)ws)[id] = pk.u;
}

__device__ __forceinline__ int cbt_idx(int b, int k) {
    int by = b >> 8, mf = (b & 255) >> 4, cr = b & 15;
    int kc = k >> 5, kg = (k & 31) >> 3, e = k & 7;
    return (((by * NKC + kc) * 16 + mf) * 64 + kg * 16 + cr) * 8 + e;
}

// ---------------- rodrigues matching the reference exactly (+1e-8 on components)
__device__ __forceinline__ void rodrigues(float rx, float ry, float rz, float* R) {
    float ax = rx + 1e-8f, ay = ry + 1e-8f, az = rz + 1e-8f;
    float ang = sqrtf(ax * ax + ay * ay + az * az);
    float inv = 1.f / ang;
    float ux = rx * inv, uy = ry * inv, uz = rz * inv;
    float s = sinf(ang), c = cosf(ang), m = 1.f - c;
    R[0] = 1.f + m * (-uz * uz - uy * uy);
    R[1] = -s * uz + m * ux * uy;
    R[2] =  s * uy + m * ux * uz;
    R[3] =  s * uz + m * ux * uy;
    R[4] = 1.f + m * (-uz * uz - ux * ux);
    R[5] = -s * ux + m * uy * uz;
    R[6] = -s * uy + m * ux * uz;
    R[7] =  s * ux + m * uy * uz;
    R[8] = 1.f + m * (-uy * uy - ux * ux);
}

// ---------------- K5: per-batch work, 4-wave K-split for joints (R12-verbatim)
__global__ void __launch_bounds__(256) k_batch(
    const float* __restrict__ gp, const float* __restrict__ npo,
    const float* __restrict__ jp, const float* __restrict__ ep,
    const float* __restrict__ sh, const float* __restrict__ ex,
    float* __restrict__ out, float* __restrict__ ws) {
    __shared__ float js_l[6000];
    __shared__ float jtp[4][64][15];
    int tid = threadIdx.x;
    int w = tid >> 6, lane = tid & 63;
    int b = blockIdx.x * 64 + lane;
    for (int s = tid; s < 6000; s += 256) js_l[s] = ws[OFF_JS + s];
    __syncthreads();
    float p15[15];
    #pragma unroll
    for (int q = 0; q < 15; ++q) p15[q] = 0.f;
    for (int i = 0; i < 100; ++i) {
        int k = 100 * w + i;
        float cl = (w < 3) ? sh[b * 300 + k] : ex[b * 100 + i];
        #pragma unroll
        for (int q = 0; q < 15; ++q) p15[q] += js_l[q * 400 + k] * cl;
    }
    #pragma unroll
    for (int q = 0; q < 15; ++q) jtp[w][lane][q] = p15[q];
    __syncthreads();
    if (w != 0) return;

    float jt[15];
    #pragma unroll
    for (int q = 0; q < 15; ++q)
        jt[q] = ws[OFF_JT + q] + jtp[0][lane][q] + jtp[1][lane][q]
              + jtp[2][lane][q] + jtp[3][lane][q];

    float R[5][9];
    rodrigues(gp[b * 3], gp[b * 3 + 1], gp[b * 3 + 2], R[0]);
    rodrigues(npo[b * 3], npo[b * 3 + 1], npo[b * 3 + 2], R[1]);
    rodrigues(jp[b * 3], jp[b * 3 + 1], jp[b * 3 + 2], R[2]);
    rodrigues(ep[b * 6], ep[b * 6 + 1], ep[b * 6 + 2], R[3]);
    rodrigues(ep[b * 6 + 3], ep[b * 6 + 4], ep[b * 6 + 5], R[4]);
    for (int j = 0; j < 5; ++j)
        for (int i = 0; i < 9; ++i)
            out[VOFF + b * 45 + j * 9 + i] = R[j][i];
    __hip_bfloat16* cb = (__hip_bfloat16*)ws;
    for (int j = 1; j < 5; ++j)
        for (int i = 0; i < 9; ++i)
            cb[cbt_idx(b, 400 + (j - 1) * 9 + i)] =
                __float2bfloat16(R[j][i] - ((i == 0 || i == 4 || i == 8) ? 1.f : 0.f));

    const int par[5] = {0, 0, 1, 1, 1};
    float rel[5][3];
    for (int k = 0; k < 3; ++k) rel[0][k] = jt[k];
    for (int j = 1; j < 5; ++j)
        for (int k = 0; k < 3; ++k) rel[j][k] = jt[j * 3 + k] - jt[par[j] * 3 + k];
    float Rc[5][9], tc[5][3];
    for (int i = 0; i < 9; ++i) Rc[0][i] = R[0][i];
    for (int k = 0; k < 3; ++k) tc[0][k] = rel[0][k];
    for (int j = 1; j < 5; ++j) {
        int p = par[j];
        for (int r = 0; r < 3; ++r) {
            for (int c2 = 0; c2 < 3; ++c2) {
                float s = 0.f;
                for (int m = 0; m < 3; ++m) s += Rc[p][r * 3 + m] * R[j][m * 3 + c2];
                Rc[j][r * 3 + c2] = s;
            }
            float tv = 0.f;
            for (int m = 0; m < 3; ++m) tv += Rc[p][r * 3 + m] * rel[j][m];
            tc[j][r] = tv + tc[p][r];
        }
    }
    for (int j = 0; j < 5; ++j)
        for (int r = 0; r < 3; ++r) {
            float tj = 0.f;
            for (int m = 0; m < 3; ++m) tj += Rc[j][r * 3 + m] * jt[j * 3 + m];
            ws[OFF_A + b * 60 + j * 12 + r * 4 + 0] = Rc[j][r * 3 + 0];
            ws[OFF_A + b * 60 + j * 12 + r * 4 + 1] = Rc[j][r * 3 + 1];
            ws[OFF_A + b * 60 + j * 12 + r * 4 + 2] = Rc[j][r * 3 + 2];
            ws[OFF_A + b * 60 + j * 12 + r * 4 + 3] = tc[j][r] - tj;
        }
}

// ---------------- K6: MFMA GEMM (256x96) + LDS-staged quartered epilogue
// Epilogue is R12-VERBATIM. ONLY delta vs R12: staging LDS diet for occupancy —
// A double-buffered (A0@0, A1@16K), B SINGLE-buffered (@32K) => 38912 B staging;
// LDS block = 40704 (epilogue overlay) -> 4 blocks/CU instead of 3.
// vmcnt derivation: tail of kc issues B(kc+1) then A(kc+2); head-of-kc queue is
// [A(kc):4, B(kc):2, A(kc+1):4] (w<3) or [A(kc):4, A(kc+1):4] (w=3);
// vmcnt(4) drains exactly through tile kc's loads in both cases.
__global__ void __launch_bounds__(256, 4) k_gemm_lbs(
    const float* __restrict__ VT, const float* __restrict__ W,
    const float* __restrict__ ws, float* __restrict__ out) {
    __shared__ __align__(16) char smem[40704];

    const char* cbt  = (const char*)ws;
    const char* sdtt = (const char*)ws + (size_t)OFF_SDTT * 4;
    const float* Amat = ws + OFF_A;

    // bijective XCD-chunked swizzle: 1256 = 8 * 157
    int flat = blockIdx.x;
    int nid = (flat & 7) * 157 + (flat >> 3);
    int bx = nid >> 3, by = nid & 7;
    int n0 = bx * BN, b0 = by * BM, v0 = bx * 32;

    int tid = threadIdx.x;
    int w = tid >> 6, lane = tid & 63;

    const char* Aglb = cbt + (size_t)(by * NKC) * 16384;
    const char* Bglb = sdtt + (size_t)(bx * NKC) * 6144;

    auto stageB = [&](int kc) {                  // B single buffer @32768
        char* lB = smem + 32768;
        const char* gb = Bglb + (size_t)kc * 6144;
        if (w < 3) {
            #pragma unroll
            for (int c = 0; c < 2; ++c) {
                int ch = 2 * w + c;
                GLDS16(gb + ch * 1024 + lane * 16, lB + ch * 1024);
            }
        }
    };
    auto stageA = [&](int kc, int p) {           // A double buffer @0 / @16384
        char* lA = smem + p * 16384;
        const char* ga = Aglb + (size_t)kc * 16384;
        #pragma unroll
        for (int c = 0; c < 4; ++c) {
            int ch = 4 * w + c;
            GLDS16(ga + ch * 1024 + lane * 16, lA + ch * 1024);
        }
    };

    // prologue: B(0), A(0), A(1)  (B first -> vmcnt(4) drains B(0)+A(0))
    stageB(0);
    stageA(0, 0);
    stageA(1, 1);

    f32x4 acc[4][6];
    #pragma unroll
    for (int m = 0; m < 4; ++m)
        #pragma unroll
        for (int j = 0; j < 6; ++j) acc[m][j] = (f32x4){0.f, 0.f, 0.f, 0.f};

    for (int kc = 0; kc < NKC; ++kc) {
        if (kc < NKC - 1)
            asm volatile("s_waitcnt vmcnt(4)" ::: "memory");
        else
            asm volatile("s_waitcnt vmcnt(0)" ::: "memory");
        __builtin_amdgcn_s_barrier();
        const char* lA = smem + (kc & 1) * 16384;
        const char* lB = smem + 32768;
        short8 af[4];
        #pragma unroll
        for (int m = 0; m < 4; ++m)
            af[m] = *(const short8*)(lA + (4 * w + m) * 1024 + lane * 16);
        #pragma unroll
        for (int j = 0; j < 6; ++j) {
            short8 bf = *(const short8*)(lB + j * 1024 + lane * 16);
            #pragma unroll
            for (int m = 0; m < 4; ++m)
                acc[m][j] = __builtin_amdgcn_mfma_f32_16x16x32_bf16(af[m], bf, acc[m][j], 0, 0, 0);
        }
        __builtin_amdgcn_s_barrier();
        if (kc + 1 < NKC) stageB(kc + 1);        // B before A (vmcnt counting)
        if (kc + 2 < NKC) stageA(kc + 2, kc & 1);
    }
    // after trailing barrier of kc=13, all LDS reads are done -> safe to overlay

    float vt6[6];
    #pragma unroll
    for (int j = 0; j < 6; ++j) {
        int n = n0 + 16 * j + (lane & 15);
        vt6[j] = (n < N3) ? VT[n] : 0.f;
    }
    int vl = tid & 31, v = v0 + vl;
    bool vok = v < V_;
    float w5[5] = {0.f, 0.f, 0.f, 0.f, 0.f};
    if (vok)
        #pragma unroll
        for (int j = 0; j < 5; ++j) w5[j] = W[v * 5 + j];

    float* Am = (float*)smem;                    // [64][60]
    float* Ps = (float*)(smem + 15872);          // [64][98]

    #pragma unroll
    for (int h = 0; h < 4; ++h) {
        // cooperative stage of this quarter's A-mats (coalesced float4)
        const float4* Ag = (const float4*)&Amat[(b0 + 64 * h) * 60];
        for (int s = tid; s < 960; s += 256)
            ((float4*)Am)[s] = Ag[s];
        // owner wave writes its Ps quarter
        if (w == h) {
            #pragma unroll
            for (int j = 0; j < 6; ++j) {
                int col = 16 * j + (lane & 15);
                #pragma unroll
                for (int m = 0; m < 4; ++m) {
                    int lrow = 16 * m + 4 * (lane >> 4);
                    #pragma unroll
                    for (int i = 0; i < 4; ++i)
                        Ps[(lrow + i) * 98 + col] = acc[m][j][i] + vt6[j];
                }
            }
        }
        __syncthreads();
        #pragma unroll 2
        for (int q = 0; q < 8; ++q) {
            int bl = (tid >> 5) + 8 * q;
            float px = Ps[bl * 98 + 3 * vl + 0];
            float py = Ps[bl * 98 + 3 * vl + 1];
            float pz = Ps[bl * 98 + 3 * vl + 2];
            if (vok) {
                const float4* Aq = (const float4*)&Am[bl * 60];
                float4 t0 = {0,0,0,0}, t1 = {0,0,0,0}, t2 = {0,0,0,0};
                #pragma unroll
                for (int j = 0; j < 5; ++j) {
                    float wj = w5[j];
                    float4 a0 = Aq[j * 3 + 0], a1 = Aq[j * 3 + 1], a2 = Aq[j * 3 + 2];
                    t0.x += wj * a0.x; t0.y += wj * a0.y; t0.z += wj * a0.z; t0.w += wj * a0.w;
                    t1.x += wj * a1.x; t1.y += wj * a1.y; t1.z += wj * a1.z; t1.w += wj * a1.w;
                    t2.x += wj * a2.x; t2.y += wj * a2.y; t2.z += wj * a2.z; t2.w += wj * a2.w;
                }
                int b = b0 + 64 * h + bl;
                int ob = b * N3 + v * 3;
                out[ob + 0] = t0.x * px + t0.y * py + t0.z * pz + t0.w;
                out[ob + 1] = t1.x * px + t1.y * py + t1.z * pz + t1.w;
                out[ob + 2] = t2.x * px + t2.y * py + t2.z * pz + t2.w;
            }
        }
        __syncthreads();
    }
}

extern "C" void kernel_launch(void* const* d_in, const int* in_sizes, int n_in,
                              void* d_out, int out_size, void* d_ws, size_t ws_size,
                              hipStream_t stream) {
    const float* shape = (const float*)d_in[0];
    const float* expr  = (const float*)d_in[1];
    const float* gpose = (const float*)d_in[2];
    const float* npose = (const float*)d_in[3];
    const float* jpose = (const float*)d_in[4];
    const float* epose = (const float*)d_in[5];
    const float* vt    = (const float*)d_in[6];
    const float* sd    = (const float*)d_in[7];
    const float* pd    = (const float*)d_in[8];
    const float* jreg  = (const float*)d_in[9];
    const float* w     = (const float*)d_in[10];
    float* out = (float*)d_out;
    float* ws  = (float*)d_ws;

    k_js<<<NCH, 512, 0, stream>>>(jreg, sd, vt, ws);
    k_js_reduce<<<24, 256, 0, stream>>>(ws);
    k_sdt_lds<<<NBX * 6, 256, 0, stream>>>(sd, pd, ws);
    k_cbt_tiled<<<(NBY * NKC * 16 * 64 + 255) / 256, 256, 0, stream>>>(shape, expr, ws);
    k_batch<<<32, 256, 0, stream>>>(gpose, npose, jpose, epose, shape, expr, out, ws);
    k_gemm_lbs<<<NBX * NBY, 256, 0, stream>>>(vt, w, ws, out);
}

// Round 18
// 124.532 us; speedup vs baseline: 1.5819x; 1.5819x over previous
//
#include <hip/hip_runtime.h>
#include <hip/hip_bf16.h>
#include <math.h>

#define B_    2048
#define V_    5023
#define N3    15069      // V*3
#define VOFF  30861312   // B_*N3, start of rot_mats in d_out

// GEMM geometry: block = 256 rows x 96 cols, 4 waves (each 64 rows), BK=32
#define BM    256
#define BN    96
#define NKC   14         // 448/32
#define NBX   157
#define NBY   8

// ws layout (float units)
#define OFF_CBT    0           // bf16 Cmat tiled: 8*14*16KB = 1835008 B
#define OFF_SDTT   458752      // bf16 SDT tiled: 157*14*6KB
#define OFF_JSP    0           // overlay: [512][6016] partials (consumed before CBT/SDTT written)
#define OFF_JS     3834880     // [15*400]
#define OFF_JT     3840880     // [15]
#define OFF_A      3840896     // [2048][60]

#define NCH 512
#define CHV 10

typedef __attribute__((ext_vector_type(8))) short short8;
typedef __attribute__((ext_vector_type(4))) float f32x4;

typedef __attribute__((address_space(1))) const void gvoid_t;
typedef __attribute__((address_space(3))) void lvoid_t;
#define GLDS16(g, l) __builtin_amdgcn_global_load_lds((gvoid_t*)(g), (lvoid_t*)(l), 16, 0, 0)

// ---------------- K1: JS/Jt partials; SD streamed once; [ch][6016] coalesced writes
__global__ void __launch_bounds__(512) k_js(
    const float* __restrict__ Jreg, const float* __restrict__ SD,
    const float* __restrict__ VT, float* __restrict__ ws) {
    int ch = blockIdx.x;
    int v0 = ch * CHV;
    int t = threadIdx.x;
    __shared__ float jw[5][CHV];
    for (int s = t; s < 5 * CHV; s += 512) {
        int j = s / CHV, vi = s % CHV;
        int v = v0 + vi;
        jw[j][vi] = (v < V_) ? Jreg[j * V_ + v] : 0.f;
    }
    __syncthreads();
    int nv = min(V_ - v0, CHV);
    if (t < 400) {
        float acc[15];
        #pragma unroll
        for (int i = 0; i < 15; ++i) acc[i] = 0.f;
        for (int vi = 0; vi < nv; ++vi) {
            int v = v0 + vi;
            float s0 = SD[(v * 3 + 0) * 400 + t];
            float s1 = SD[(v * 3 + 1) * 400 + t];
            float s2 = SD[(v * 3 + 2) * 400 + t];
            #pragma unroll
            for (int j = 0; j < 5; ++j) {
                float jr = jw[j][vi];
                acc[j * 3 + 0] += jr * s0;
                acc[j * 3 + 1] += jr * s1;
                acc[j * 3 + 2] += jr * s2;
            }
        }
        #pragma unroll
        for (int i = 0; i < 15; ++i)
            ws[OFF_JSP + ch * 6016 + i * 400 + t] = acc[i];   // coalesced in t
    } else if (t >= 448 && t < 463) {
        int jk = t - 448, j = jk / 3, k = jk % 3;
        float a = 0.f;
        for (int vi = 0; vi < nv; ++vi)
            a += jw[j][vi] * VT[(v0 + vi) * 3 + k];
        ws[OFF_JSP + ch * 6016 + 6000 + jk] = a;
    }
}

// ---------------- K2: reduce partials ([ch][6016] -> coalesced reads across r)
__global__ void k_js_reduce(float* __restrict__ ws) {
    int r = blockIdx.x * 256 + threadIdx.x;
    if (r >= 6016) return;
    float s = 0.f;
    for (int ch = 0; ch < NCH; ++ch) s += ws[OFF_JSP + ch * 6016 + r];
    if (r < 6000) ws[OFF_JS + r] = s;
    else if (r < 6015) ws[OFF_JT + (r - 6000)] = s;
}

// ---------------- K3: SDT fragment-tiled via LDS transpose — SD read COALESCED
__global__ void __launch_bounds__(256) k_sdt_lds(
    const float* __restrict__ SD, const float* __restrict__ PD,
    float* __restrict__ ws) {
    __shared__ __hip_bfloat16 lb[16][456];   // row stride 912 B (16B-aligned)
    int bid = blockIdx.x;
    int bx = bid / 6, jl = bid % 6;
    int n0 = bx * 96 + jl * 16;
    int tid = threadIdx.x;
    for (int s = tid; s < 16 * 400; s += 256) {
        int r = s / 400, c = s % 400;
        int n = n0 + r;
        lb[r][c] = __float2bfloat16((n < N3) ? SD[n * 400 + c] : 0.f);
    }
    for (int s = tid; s < 36 * 16; s += 256) {
        int p = s / 16, r = s % 16;
        int n = n0 + r;
        lb[r][400 + p] = __float2bfloat16((n < N3) ? PD[p * N3 + n] : 0.f);
    }
    for (int s = tid; s < 12 * 16; s += 256) {
        int c = s / 16, r = s % 16;
        lb[r][436 + c] = __float2bfloat16(0.f);
    }
    __syncthreads();
    uint4* sdtt = (uint4*)((char*)ws + (size_t)OFF_SDTT * 4);
    for (int s = tid; s < NKC * 64; s += 256) {
        int kc = s >> 6, lane = s & 63;
        int r = lane & 15;
        int k0 = kc * 32 + (lane >> 4) * 8;
        uint4 val = *(const uint4*)&lb[r][k0];
        sdtt[((size_t)(bx * NKC + kc) * 6 + jl) * 64 + lane] = val;
    }
}

// ---------------- K4: Cmat (betas) in fragment-tiled order
__global__ void k_cbt_tiled(const float* __restrict__ sh, const float* __restrict__ ex,
                            float* __restrict__ ws) {
    int id = blockIdx.x * 256 + threadIdx.x;
    if (id >= NBY * NKC * 16 * 64) return;
    int lane = id & 63;
    int t = id >> 6;
    int mf = t & 15; t >>= 4;
    int kc = t % NKC, by = t / NKC;
    int b = by * BM + mf * 16 + (lane & 15);
    int k0 = kc * 32 + (lane >> 4) * 8;
    union { __hip_bfloat16 h[8]; uint4 u; } pk;
    #pragma unroll
    for (int e = 0; e < 8; ++e) {
        int k = k0 + e;
        float v = 0.f;
        if (k < 300) v = sh[b * 300 + k];
        else if (k < 400) v = ex[b * 100 + (k - 300)];
        pk.h[e] = __float2bfloat16(v);
    }
    ((uint4*)ws)[id] = pk.u;
}

__device__ __forceinline__ int cbt_idx(int b, int k) {
    int by = b >> 8, mf = (b & 255) >> 4, cr = b & 15;
    int kc = k >> 5, kg = (k & 31) >> 3, e = k & 7;
    return (((by * NKC + kc) * 16 + mf) * 64 + kg * 16 + cr) * 8 + e;
}

// ---------------- rodrigues matching the reference exactly (+1e-8 on components)
__device__ __forceinline__ void rodrigues(float rx, float ry, float rz, float* R) {
    float ax = rx + 1e-8f, ay = ry + 1e-8f, az = rz + 1e-8f;
    float ang = sqrtf(ax * ax + ay * ay + az * az);
    float inv = 1.f / ang;
    float ux = rx * inv, uy = ry * inv, uz = rz * inv;
    float s = sinf(ang), c = cosf(ang), m = 1.f - c;
    R[0] = 1.f + m * (-uz * uz - uy * uy);
    R[1] = -s * uz + m * ux * uy;
    R[2] =  s * uy + m * ux * uz;
    R[3] =  s * uz + m * ux * uy;
    R[4] = 1.f + m * (-uz * uz - ux * ux);
    R[5] = -s * ux + m * uy * uz;
    R[6] = -s * uy + m * ux * uz;
    R[7] =  s * ux + m * uy * uz;
    R[8] = 1.f + m * (-uy * uy - ux * ux);
}

// ---------------- K5: per-batch work, 4-wave K-split for joints
__global__ void __launch_bounds__(256) k_batch(
    const float* __restrict__ gp, const float* __restrict__ npo,
    const float* __restrict__ jp, const float* __restrict__ ep,
    const float* __restrict__ sh, const float* __restrict__ ex,
    float* __restrict__ out, float* __restrict__ ws) {
    __shared__ float js_l[6000];
    __shared__ float jtp[4][64][15];
    int tid = threadIdx.x;
    int w = tid >> 6, lane = tid & 63;
    int b = blockIdx.x * 64 + lane;
    for (int s = tid; s < 6000; s += 256) js_l[s] = ws[OFF_JS + s];
    __syncthreads();
    float p15[15];
    #pragma unroll
    for (int q = 0; q < 15; ++q) p15[q] = 0.f;
    for (int i = 0; i < 100; ++i) {
        int k = 100 * w + i;
        float cl = (w < 3) ? sh[b * 300 + k] : ex[b * 100 + i];
        #pragma unroll
        for (int q = 0; q < 15; ++q) p15[q] += js_l[q * 400 + k] * cl;
    }
    #pragma unroll
    for (int q = 0; q < 15; ++q) jtp[w][lane][q] = p15[q];
    __syncthreads();
    if (w != 0) return;

    float jt[15];
    #pragma unroll
    for (int q = 0; q < 15; ++q)
        jt[q] = ws[OFF_JT + q] + jtp[0][lane][q] + jtp[1][lane][q]
              + jtp[2][lane][q] + jtp[3][lane][q];

    float R[5][9];
    rodrigues(gp[b * 3], gp[b * 3 + 1], gp[b * 3 + 2], R[0]);
    rodrigues(npo[b * 3], npo[b * 3 + 1], npo[b * 3 + 2], R[1]);
    rodrigues(jp[b * 3], jp[b * 3 + 1], jp[b * 3 + 2], R[2]);
    rodrigues(ep[b * 6], ep[b * 6 + 1], ep[b * 6 + 2], R[3]);
    rodrigues(ep[b * 6 + 3], ep[b * 6 + 4], ep[b * 6 + 5], R[4]);
    for (int j = 0; j < 5; ++j)
        for (int i = 0; i < 9; ++i)
            out[VOFF + b * 45 + j * 9 + i] = R[j][i];
    __hip_bfloat16* cb = (__hip_bfloat16*)ws;
    for (int j = 1; j < 5; ++j)
        for (int i = 0; i < 9; ++i)
            cb[cbt_idx(b, 400 + (j - 1) * 9 + i)] =
                __float2bfloat16(R[j][i] - ((i == 0 || i == 4 || i == 8) ? 1.f : 0.f));

    const int par[5] = {0, 0, 1, 1, 1};
    float rel[5][3];
    for (int k = 0; k < 3; ++k) rel[0][k] = jt[k];
    for (int j = 1; j < 5; ++j)
        for (int k = 0; k < 3; ++k) rel[j][k] = jt[j * 3 + k] - jt[par[j] * 3 + k];
    float Rc[5][9], tc[5][3];
    for (int i = 0; i < 9; ++i) Rc[0][i] = R[0][i];
    for (int k = 0; k < 3; ++k) tc[0][k] = rel[0][k];
    for (int j = 1; j < 5; ++j) {
        int p = par[j];
        for (int r = 0; r < 3; ++r) {
            for (int c2 = 0; c2 < 3; ++c2) {
                float s = 0.f;
                for (int m = 0; m < 3; ++m) s += Rc[p][r * 3 + m] * R[j][m * 3 + c2];
                Rc[j][r * 3 + c2] = s;
            }
            float tv = 0.f;
            for (int m = 0; m < 3; ++m) tv += Rc[p][r * 3 + m] * rel[j][m];
            tc[j][r] = tv + tc[p][r];
        }
    }
    for (int j = 0; j < 5; ++j)
        for (int r = 0; r < 3; ++r) {
            float tj = 0.f;
            for (int m = 0; m < 3; ++m) tj += Rc[j][r * 3 + m] * jt[j * 3 + m];
            ws[OFF_A + b * 60 + j * 12 + r * 4 + 0] = Rc[j][r * 3 + 0];
            ws[OFF_A + b * 60 + j * 12 + r * 4 + 1] = Rc[j][r * 3 + 1];
            ws[OFF_A + b * 60 + j * 12 + r * 4 + 2] = Rc[j][r * 3 + 2];
            ws[OFF_A + b * 60 + j * 12 + r * 4 + 3] = tc[j][r] - tj;
        }
}

// ---------------- K6: MFMA GEMM (256x96) + LDS-staged quartered epilogue
// (R12-VERBATIM — the verified best; do not modify)
__global__ void __launch_bounds__(256, 3) k_gemm_lbs(
    const float* __restrict__ VT, const float* __restrict__ W,
    const float* __restrict__ ws, float* __restrict__ out) {
    __shared__ __align__(16) char smem[45056];

    const char* cbt  = (const char*)ws;
    const char* sdtt = (const char*)ws + (size_t)OFF_SDTT * 4;
    const float* Amat = ws + OFF_A;

    // bijective XCD-chunked swizzle: 1256 = 8 * 157
    int flat = blockIdx.x;
    int nid = (flat & 7) * 157 + (flat >> 3);
    int bx = nid >> 3, by = nid & 7;
    int n0 = bx * BN, b0 = by * BM, v0 = bx * 32;

    int tid = threadIdx.x;
    int w = tid >> 6, lane = tid & 63;

    const char* Aglb = cbt + (size_t)(by * NKC) * 16384;
    const char* Bglb = sdtt + (size_t)(bx * NKC) * 6144;

    auto stage = [&](int kc, int p) {
        char* lA = smem + p * 22528;
        char* lB = lA + 16384;
        const char* ga = Aglb + (size_t)kc * 16384;
        const char* gb = Bglb + (size_t)kc * 6144;
        #pragma unroll
        for (int c = 0; c < 4; ++c) {
            int ch = 4 * w + c;
            GLDS16(ga + ch * 1024 + lane * 16, lA + ch * 1024);
        }
        if (w < 3) {
            #pragma unroll
            for (int c = 0; c < 2; ++c) {
                int ch = 2 * w + c;
                GLDS16(gb + ch * 1024 + lane * 16, lB + ch * 1024);
            }
        }
    };

    stage(0, 0);
    stage(1, 1);

    f32x4 acc[4][6];
    #pragma unroll
    for (int m = 0; m < 4; ++m)
        #pragma unroll
        for (int j = 0; j < 6; ++j) acc[m][j] = (f32x4){0.f, 0.f, 0.f, 0.f};

    for (int kc = 0; kc < NKC; ++kc) {
        int p = kc & 1;
        if (kc < NKC - 1) {
            if (w < 3) asm volatile("s_waitcnt vmcnt(6)" ::: "memory");
            else       asm volatile("s_waitcnt vmcnt(4)" ::: "memory");
        } else {
            asm volatile("s_waitcnt vmcnt(0)" ::: "memory");
        }
        __builtin_amdgcn_s_barrier();
        const char* lA = smem + p * 22528;
        const char* lB = lA + 16384;
        short8 af[4];
        #pragma unroll
        for (int m = 0; m < 4; ++m)
            af[m] = *(const short8*)(lA + (4 * w + m) * 1024 + lane * 16);
        #pragma unroll
        for (int j = 0; j < 6; ++j) {
            short8 bf = *(const short8*)(lB + j * 1024 + lane * 16);
            #pragma unroll
            for (int m = 0; m < 4; ++m)
                acc[m][j] = __builtin_amdgcn_mfma_f32_16x16x32_bf16(af[m], bf, acc[m][j], 0, 0, 0);
        }
        __builtin_amdgcn_s_barrier();
        if (kc + 2 < NKC) stage(kc + 2, p);
    }
    // after trailing barrier of kc=13, all LDS reads are done -> safe to overlay

    float vt6[6];
    #pragma unroll
    for (int j = 0; j < 6; ++j) {
        int n = n0 + 16 * j + (lane & 15);
        vt6[j] = (n < N3) ? VT[n] : 0.f;
    }
    int vl = tid & 31, v = v0 + vl;
    bool vok = v < V_;
    float w5[5] = {0.f, 0.f, 0.f, 0.f, 0.f};
    if (vok)
        #pragma unroll
        for (int j = 0; j < 5; ++j) w5[j] = W[v * 5 + j];

    float* Am = (float*)smem;                    // [64][60]
    float* Ps = (float*)(smem + 15872);          // [64][98]

    #pragma unroll
    for (int h = 0; h < 4; ++h) {
        // cooperative stage of this quarter's A-mats (coalesced float4)
        const float4* Ag = (const float4*)&Amat[(b0 + 64 * h) * 60];
        for (int s = tid; s < 960; s += 256)
            ((float4*)Am)[s] = Ag[s];
        // owner wave writes its Ps quarter
        if (w == h) {
            #pragma unroll
            for (int j = 0; j < 6; ++j) {
                int col = 16 * j + (lane & 15);
                #pragma unroll
                for (int m = 0; m < 4; ++m) {
                    int lrow = 16 * m + 4 * (lane >> 4);
                    #pragma unroll
                    for (int i = 0; i < 4; ++i)
                        Ps[(lrow + i) * 98 + col] = acc[m][j][i] + vt6[j];
                }
            }
        }
        __syncthreads();
        #pragma unroll 2
        for (int q = 0; q < 8; ++q) {
            int bl = (tid >> 5) + 8 * q;
            float px = Ps[bl * 98 + 3 * vl + 0];
            float py = Ps[bl * 98 + 3 * vl + 1];
            float pz = Ps[bl * 98 + 3 * vl + 2];
            if (vok) {
                const float4* Aq = (const float4*)&Am[bl * 60];
                float4 t0 = {0,0,0,0}, t1 = {0,0,0,0}, t2 = {0,0,0,0};
                #pragma unroll
                for (int j = 0; j < 5; ++j) {
                    float wj = w5[j];
                    float4 a0 = Aq[j * 3 + 0], a1 = Aq[j * 3 + 1], a2 = Aq[j * 3 + 2];
                    t0.x += wj * a0.x; t0.y += wj * a0.y; t0.z += wj * a0.z; t0.w += wj * a0.w;
                    t1.x += wj * a1.x; t1.y += wj * a1.y; t1.z += wj * a1.z; t1.w += wj * a1.w;
                    t2.x += wj * a2.x; t2.y += wj * a2.y; t2.z += wj * a2.z; t2.w += wj * a2.w;
                }
                int b = b0 + 64 * h + bl;
                int ob = b * N3 + v * 3;
                out[ob + 0] = t0.x * px + t0.y * py + t0.z * pz + t0.w;
                out[ob + 1] = t1.x * px + t1.y * py + t1.z * pz + t1.w;
                out[ob + 2] = t2.x * px + t2.y * py + t2.z * pz + t2.w;
            }
        }
        __syncthreads();
    }
}

extern "C" void kernel_launch(void* const* d_in, const int* in_sizes, int n_in,
                              void* d_out, int out_size, void* d_ws, size_t ws_size,
                              hipStream_t stream) {
    const float* shape = (const float*)d_in[0];
    const float* expr  = (const float*)d_in[1];
    const float* gpose = (const float*)d_in[2];
    const float* npose = (const float*)d_in[3];
    const float* jpose = (const float*)d_in[4];
    const float* epose = (const float*)d_in[5];
    const float* vt    = (const float*)d_in[6];
    const float* sd    = (const float*)d_in[7];
    const float* pd    = (const float*)d_in[8];
    const float* jreg  = (const float*)d_in[9];
    const float* w     = (const float*)d_in[10];
    float* out = (float*)d_out;
    float* ws  = (float*)d_ws;

    k_js<<<NCH, 512, 0, stream>>>(jreg, sd, vt, ws);
    k_js_reduce<<<24, 256, 0, stream>>>(ws);
    k_sdt_lds<<<NBX * 6, 256, 0, stream>>>(sd, pd, ws);
    k_cbt_tiled<<<(NBY * NKC * 16 * 64 + 255) / 256, 256, 0, stream>>>(shape, expr, ws);
    k_batch<<<32, 256, 0, stream>>>(gpose, npose, jpose, epose, shape, expr, out, ws);
    k_gemm_lbs<<<NBX * NBY, 256, 0, stream>>>(vt, w, ws, out);
}